// Round 4
// baseline (312.429 us; speedup 1.0000x reference)
//
#include <hip/hip_runtime.h>
#include <hip/hip_bf16.h>

#define B_   4
#define L_   1024
#define D_   1280
#define H_   20
#define DH_  64
#define BH_  (B_*H_)     // 80
#define L2_  (2*L_)      // 2048
#define ALPHA_ 0.48f
// Q prescale: 0.125 (score scale) * log2(e) -> scores in log2 domain, exp = v_exp_f32
#define QSCALE_ 0.180336880f

typedef __attribute__((ext_vector_type(8))) short short8;
typedef __attribute__((ext_vector_type(4))) float float4v;

__device__ __forceinline__ float exp2_fast(float x) {
    float r;
    asm volatile("v_exp_f32 %0, %1" : "=v"(r) : "v"(x));
    return r;
}

__device__ __forceinline__ ushort f2bf(float f) {
    union { float f; unsigned int i; } v; v.f = f;
    unsigned int i = v.i;
    unsigned int r = i + 0x7FFF + ((i >> 16) & 1);  // RNE
    return (ushort)(r >> 16);
}
__device__ __forceinline__ short8 pack8(float4 f0, float4 f1) {
    short8 o;
    o[0] = (short)f2bf(f0.x); o[1] = (short)f2bf(f0.y);
    o[2] = (short)f2bf(f0.z); o[3] = (short)f2bf(f0.w);
    o[4] = (short)f2bf(f1.x); o[5] = (short)f2bf(f1.y);
    o[6] = (short)f2bf(f1.z); o[7] = (short)f2bf(f1.w);
    return o;
}
// pack 4 f32 -> 4 bf16 (RNE) and store as one 8-byte write
__device__ __forceinline__ void pack4_store(ushort* dst, float a, float b, float c, float d) {
    union { __hip_bfloat162 h; unsigned int u; } x, y;
    x.h = __float22bfloat162_rn(make_float2(a, b));
    y.h = __float22bfloat162_rn(make_float2(c, d));
    uint2 v; v.x = x.u; v.y = y.u;
    *(uint2*)dst = v;
}

// async global->LDS, 16 B per lane; dest = wave-uniform base + lane*16
__device__ __forceinline__ void async16(const void* g, void* l) {
    __builtin_amdgcn_global_load_lds(
        (__attribute__((address_space(1))) void*)g,
        (__attribute__((address_space(3))) void*)l, 16, 0, 0);
}

// ---------------- fused prep (inputs f32) -------------------------------------------
// K/V stored in flash-staging tile order so flash's global_load_lds is coalesced:
//   Kc tile  [bh][kt]      : elem (c*64 + kv)*8 + e  = bf16(K[kt*64+kv][c*8+e])
//   Vc tile  [bh][kt 0..31]: elem (cc*64 + d)*8 + e  = bf16((a)V[kt*64+cc*8+e][d])
// bi <  1600 : Wt[z][c][r] = bf16(w_z[r][c])          (weight transposes)
// bi <  2880 : Vc bg tiles (kt 16..31) from Vbg, alpha-scaled
// bi <  5440 : Xb  = bf16(X)
// bi <  6720 : Kc bg tiles from Kbg (unscaled; alpha applied on log2-scores in flash)
__global__ __launch_bounds__(256) void prep(
    const float* __restrict__ w0, const float* __restrict__ w1,
    const float* __restrict__ w2, const float* __restrict__ w3,
    ushort* __restrict__ Wt,
    const float* __restrict__ Vbg, ushort* __restrict__ Vt,
    const float* __restrict__ X, ushort* __restrict__ Xb,
    const float* __restrict__ Kbg, ushort* __restrict__ Kcv) {
    int bi = blockIdx.x, tid = threadIdx.x;
    __shared__ __align__(16) ushort t[64 * 72];
    if (bi < 2880) {
        bool doScale = (bi >= 1600);
        const float* src; int srcld; long sbase;
        ushort* dst = nullptr; int dstld = 0; long dbase = 0;  // W path
        ushort* vout = nullptr;                                // V path
        if (bi < 1600) {
            int z = bi / 400, t4 = bi % 400;
            int by = t4 / 20, bx = t4 % 20;
            const float* srcs[4] = {w0, w1, w2, w3};
            src = srcs[z]; srcld = D_; dstld = D_;
            sbase = (long)(by * 64) * D_ + bx * 64;
            dst = Wt + (long)z * D_ * D_;
            dbase = (long)(bx * 64) * D_ + by * 64;
        } else {
            int j = bi - 1600;          // 0..1279
            int bh = j >> 4, kt = j & 15;
            src = Vbg; srcld = DH_;
            sbase = ((long)bh * L_ + kt * 64) * DH_;
            vout = Vt + (((long)bh * 32 + 16 + kt) << 12);
        }
        int ldr = tid >> 3, ldc = (tid & 7) * 8;
#pragma unroll
        for (int i = 0; i < 2; i++) {
            int y = ldr + 32 * i;
            long idx = sbase + (long)y * srcld + ldc;
            float4 f0 = *(const float4*)&src[idx];
            float4 f1 = *(const float4*)&src[idx + 4];
            if (doScale) {
                f0.x *= ALPHA_; f0.y *= ALPHA_; f0.z *= ALPHA_; f0.w *= ALPHA_;
                f1.x *= ALPHA_; f1.y *= ALPHA_; f1.z *= ALPHA_; f1.w *= ALPHA_;
            }
            *(short8*)&t[y * 72 + ldc] = pack8(f0, f1);
        }
        __syncthreads();
        if (bi < 1600) {
            int r8 = (tid & 7) * 8, c0 = tid >> 3;   // coalesced: wave covers 8 c-rows
#pragma unroll
            for (int i = 0; i < 2; i++) {
                int c = c0 + i * 32;
                short8 o;
#pragma unroll
                for (int j2 = 0; j2 < 8; j2++) o[j2] = (short)t[(r8 + j2) * 72 + c];
                *(short8*)&dst[dbase + (long)c * dstld + r8] = o;
            }
        } else {
            // Vc tile: out chunk jj = cc*64 + d  <-  t[kv=cc*8+e][d]
#pragma unroll
            for (int i = 0; i < 2; i++) {
                int jj = i * 256 + tid;
                int cc = jj >> 6, d2 = jj & 63;
                short8 o;
#pragma unroll
                for (int e = 0; e < 8; e++) o[e] = (short)t[(cc * 8 + e) * 72 + d2];
                *(short8*)&vout[(long)jj * 8] = o;
            }
        }
    } else if (bi < 5440) {
        long i = ((long)(bi - 2880) * 256 + tid) * 8;
        *(short8*)&Xb[i] = pack8(*(const float4*)&X[i], *(const float4*)&X[i + 4]);
    } else {
        // Kc bg tile permute: 16B-chunk reorder via LDS (coalesced both sides)
        int j2 = bi - 5440;             // 0..1279
        int bh = j2 >> 4, kt = j2 & 15;
        const float* src = Kbg + ((long)bh * L_ + kt * 64) * DH_;
#pragma unroll
        for (int i = 0; i < 2; i++) {
            int r = i * 256 + tid;      // chunk (kv, cd): coalesced 32B f32 reads
            int kv = r >> 3, cd = r & 7;
            long idx = (long)kv * 64 + cd * 8;
            *(short8*)&t[kv * 72 + cd * 8] =
                pack8(*(const float4*)&src[idx], *(const float4*)&src[idx + 4]);
        }
        __syncthreads();
        ushort* outp = Kcv + (((long)bh * 16 + kt) << 12);
#pragma unroll
        for (int i = 0; i < 2; i++) {
            int jj = i * 256 + tid;     // out chunk jj = c*64 + kv: coalesced writes
            int c = jj >> 6, kv = jj & 63;
            *(short8*)&outp[(long)jj * 8] = *(const short8*)&t[kv * 72 + c * 8];
        }
    }
}

// ---------------- GEMM (bf16): C[m][n] = sum_k A[m][k]*Bt[n][k], K=1280 --------------
// Double-buffered async LDS staging, one barrier per K-iter (R7 config).
// mode 0: scatter -> Qp (x QSCALE_), Kc tiles, Vc tiles
// mode 1: Out(f32) = acc + bo[n]
template<int BMt, int BNt, int WROWS, int WCOLS>
__global__ __launch_bounds__(256) void gemm_tpl(
    const ushort* __restrict__ A, const ushort* __restrict__ Bt,
    ushort* __restrict__ Qp, ushort* __restrict__ Kp, ushort* __restrict__ Vt,
    float* __restrict__ Out, const float* __restrict__ bo, int mode) {
    constexpr int MI = BMt / WROWS / 16;
    constexpr int NI = BNt / WCOLS / 16;
    constexpr int ASZ = BMt * 32, BSZ = BNt * 32;
    constexpr int RB = 1280 / BNt;  // blocks per 1280-wide output region
    __shared__ __align__(16) ushort Al[2 * ASZ];
    __shared__ __align__(16) ushort Bl[2 * BSZ];
    int tid = threadIdx.x;
    int bx = blockIdx.x, by = blockIdx.y;
    int w = tid >> 6, lane = tid & 63, l15 = lane & 15, quad = lane >> 4;
    int wm = (w / WCOLS) * (BMt / WROWS);
    int wn = (w % WCOLS) * (BNt / WCOLS);
    float4v acc[MI][NI] = {};
    const int K = 1280;
    constexpr int NK = 40;
    const ushort* Arow = A + (long)by * BMt * K + (tid >> 2) * K + (tid & 3) * 8;
    const ushort* Brow = Bt + (long)bx * BNt * K + (tid >> 2) * K + (tid & 3) * 8;

    auto stage = [&](int ki, int b) {
#pragma unroll
        for (int i = 0; i < BMt / 64; i++)
            async16(Arow + (long)i * 64 * K + ki * 32, &Al[b * ASZ + (i * 4 + w) * 512]);
#pragma unroll
        for (int i = 0; i < BNt / 64; i++)
            async16(Brow + (long)i * 64 * K + ki * 32, &Bl[b * BSZ + (i * 4 + w) * 512]);
    };

    stage(0, 0);
    __syncthreads();
    for (int ki = 0; ki < NK; ki++) {
        int cur = ki & 1;
        if (ki + 1 < NK) stage(ki + 1, 1 - cur);
        short8 av[MI], bv[NI];
#pragma unroll
        for (int mi = 0; mi < MI; mi++)
            av[mi] = *(const short8*)&Al[cur * ASZ + (wm + mi * 16 + l15) * 32 + quad * 8];
#pragma unroll
        for (int ni = 0; ni < NI; ni++)
            bv[ni] = *(const short8*)&Bl[cur * BSZ + (wn + ni * 16 + l15) * 32 + quad * 8];
#pragma unroll
        for (int mi = 0; mi < MI; mi++)
#pragma unroll
            for (int ni = 0; ni < NI; ni++)
                acc[mi][ni] = __builtin_amdgcn_mfma_f32_16x16x32_bf16(av[mi], bv[ni], acc[mi][ni], 0, 0, 0);
        __syncthreads();
    }

    if (mode == 0) {
        int which = bx / RB;
#pragma unroll
        for (int mi = 0; mi < MI; mi++) {
            int m0 = by * BMt + wm + mi * 16 + quad * 4;
            int b = m0 >> 10, l0 = m0 & 1023;
#pragma unroll
            for (int ni = 0; ni < NI; ni++) {
                int n = bx * BNt + wn + ni * 16 + l15;
                int np = n - which * 1280;
                int h = np >> 6, dh = np & 63;
                if (which == 0) {
#pragma unroll
                    for (int r = 0; r < 4; r++)
                        Qp[((long)(b * H_ + h) * L_ + l0 + r) * DH_ + dh] =
                            f2bf(acc[mi][ni][r] * QSCALE_);
                } else if (which == 1) {
                    // Kc tile: elem ((bh*16+kt)*8 + dh/8)*512 + (kv&63)*8 + dh&7
                    long kb = ((((long)(b * H_ + h) * 16 + (l0 >> 6)) * 8 + (dh >> 3)) * 64
                               + (l0 & 63)) * 8 + (dh & 7);
#pragma unroll
                    for (int r = 0; r < 4; r++)
                        Kp[kb + r * 8] = f2bf(acc[mi][ni][r]);
                } else {
                    // Vc tile: elem ((bh*32+kt)*8 + cc)*512 + dh*8 + e, e=l0&7 in {0,4}
                    pack4_store(&Vt[((((long)(b * H_ + h) * 32 + (l0 >> 6)) * 8
                                      + ((l0 & 63) >> 3)) * 64 + dh) * 8 + (l0 & 7)],
                                acc[mi][ni][0], acc[mi][ni][1],
                                acc[mi][ni][2], acc[mi][ni][3]);
                }
            }
        }
    } else {
#pragma unroll
        for (int mi = 0; mi < MI; mi++) {
            int mloc = wm + mi * 16 + quad * 4;
#pragma unroll
            for (int ni = 0; ni < NI; ni++) {
                int nloc = wn + ni * 16 + l15;
#pragma unroll
                for (int r = 0; r < 4; r++) {
                    int m = by * BMt + mloc + r;
                    int n = bx * BNt + nloc;
                    Out[(long)m * D_ + n] = acc[mi][ni][r] + bo[n];
                }
            }
        }
    }
}

// ---------------- flash attention: split-KV, 2 blocks per (bh,qt) -------------------
// R11: grid 640 -> 1280 blocks (s=0: fg kt 0..15, s=1: bg kt 16..31). The 640-block
// grid left 2.5 blocks/CU (128 CUs with 3, 128 with 2 -> ~33% end-imbalance) and only
// 2.5 waves/SIMD of latency cover (Occupancy 20%). Split-KV halves per-block work and
// queue-balances 1280 blocks; partials (un-normalized f32 O + row-sum) combined by a
// separate streaming kernel. Inner kt loop byte-identical to R10.
#define FS 72  // Pl row stride (elems): 144 B, 16B-aligned, 2-way banks only

__global__ __launch_bounds__(256) void flash_attn(
    const ushort* __restrict__ Qp, const ushort* __restrict__ Kp,
    const ushort* __restrict__ Kbg, const ushort* __restrict__ Vt,
    float* __restrict__ Op, float* __restrict__ Rs) {
    __shared__ __align__(16) ushort Kl[2 * 4096], Vl[2 * 4096];
    __shared__ __align__(16) ushort Pl[128 * FS];
    int tid = threadIdx.x;
    int w = tid >> 6, lane = tid & 63, l15 = lane & 15, quad = lane >> 4;
    int bi = blockIdx.x;
    int s = bi >= 640; int ib = bi - s * 640;        // per-half XCD swizzle intact
    int bh = (ib & 7) * 10 + ((ib >> 3) % 10);
    int qt = ib / 80;
    const int kt0 = s * 16;

    // Q fragments: wave w owns q rows qt*128 + w*32 .. +32 (loop-invariant)
    short8 aq[2][2];
    const ushort* Qb = Qp + ((long)bh * L_ + qt * 128 + w * 32) * DH_;
#pragma unroll
    for (int mi = 0; mi < 2; mi++)
#pragma unroll
        for (int ks = 0; ks < 2; ks++)
            aq[mi][ks] = *(const short8*)&Qb[(mi * 16 + l15) * DH_ + ks * 32 + quad * 8];

    float rs[2] = {0.f, 0.f};
    float4v O[2][4] = {};
    int prow = (w * 32 + l15) * FS;  // wave-private Pl rows [w*32, w*32+32)

    auto stage = [&](int kt, int b) {  // coalesced: tile base + c*1KB + lane*16B
        const ushort* Ksrc = (kt < 16)
            ? Kp  + (((long)bh * 16 + kt) << 12)
            : Kbg + (((long)bh * 16 + (kt - 16)) << 12);
        const ushort* Vsrc = Vt + (((long)bh * 32 + kt) << 12);
#pragma unroll
        for (int i = 0; i < 2; i++) {
            int c = w * 2 + i;
            async16(&Ksrc[c * 512 + lane * 8], &Kl[b * 4096 + c * 512]);
            async16(&Vsrc[c * 512 + lane * 8], &Vl[b * 4096 + c * 512]);
        }
    };

    stage(kt0, 0);
    __syncthreads();
    for (int kt = kt0; kt < kt0 + 16; kt++) {
        int cur = kt & 1;
        if (kt + 1 < kt0 + 16) stage(kt + 1, 1 - cur);
        bool bg = (kt >= 16);
        // S^T = MFMA(A=K, B=Q): lane q = w*32+mi*16+l15, kv = nt*16+quad*4+r
        float4v s4[4][2] = {};
#pragma unroll
        for (int ks = 0; ks < 2; ks++) {
            short8 bk[4];
#pragma unroll
            for (int nt = 0; nt < 4; nt++)
                bk[nt] = *(const short8*)&Kl[cur * 4096 + (ks * 4 + quad) * 512 + (nt * 16 + l15) * 8];
#pragma unroll
            for (int nt = 0; nt < 4; nt++)
#pragma unroll
                for (int mi = 0; mi < 2; mi++)
                    s4[nt][mi] = __builtin_amdgcn_mfma_f32_16x16x32_bf16(bk[nt], aq[mi][ks], s4[nt][mi], 0, 0, 0);
        }
        // p = 2^s (alpha on bg log2-scores); rs lane-local; P packed to LDS
#pragma unroll
        for (int nt = 0; nt < 4; nt++)
#pragma unroll
            for (int mi = 0; mi < 2; mi++) {
                float p[4];
#pragma unroll
                for (int r = 0; r < 4; r++) {
                    float sv = s4[nt][mi][r];
                    if (bg) sv *= ALPHA_;
                    p[r] = exp2_fast(sv);
                    rs[mi] += p[r];
                }
                pack4_store(&Pl[prow + mi * 16 * FS + nt * 16 + quad * 4],
                            p[0], p[1], p[2], p[3]);
            }
        // per-wave LDS write->read ordering for Pl (wave-private rows)
        asm volatile("s_waitcnt lgkmcnt(0)" ::: "memory");
        __builtin_amdgcn_sched_barrier(0);
        // O^T += MFMA(A=V^T, B=P): lane q = l15 (+mi*16), d = nt*16+quad*4+r
#pragma unroll
        for (int ks = 0; ks < 2; ks++) {
            short8 bv[4];
#pragma unroll
            for (int nt = 0; nt < 4; nt++)
                bv[nt] = *(const short8*)&Vl[cur * 4096 + (ks * 4 + quad) * 512 + (nt * 16 + l15) * 8];
            short8 ap[2];
#pragma unroll
            for (int mi = 0; mi < 2; mi++)
                ap[mi] = *(const short8*)&Pl[prow + mi * 16 * FS + ks * 32 + quad * 8];
#pragma unroll
            for (int nt = 0; nt < 4; nt++)
#pragma unroll
                for (int mi = 0; mi < 2; mi++)
                    O[mi][nt] = __builtin_amdgcn_mfma_f32_16x16x32_bf16(bv[nt], ap[mi], O[mi][nt], 0, 0, 0);
        }
        __syncthreads();  // prefetch complete + all waves done with cur buffer
    }
    // rs partials live across the 4 quads of each q: reduce with 2 shuffles; store
    // un-normalized O (f32) + rs partial for the combine pass.
#pragma unroll
    for (int mi = 0; mi < 2; mi++) {
        float v = rs[mi];
        v += __shfl_xor(v, 16);
        v += __shfl_xor(v, 32);
        long l = qt * 128 + w * 32 + mi * 16 + l15;
        long row = ((long)s * BH_ + bh) * L_ + l;
#pragma unroll
        for (int nt = 0; nt < 4; nt++)
            *(float4v*)&Op[row * DH_ + nt * 16 + quad * 4] = O[mi][nt];
        if (quad == 0) Rs[row] = v;
    }
}

// ---------------- combine: Ctx = (O0+O1)/(rs0+rs1), f32 -> bf16 ---------------------
__global__ __launch_bounds__(256) void combine(
    const float* __restrict__ Op, const float* __restrict__ Rs,
    ushort* __restrict__ Ctx) {
    long idx = (long)blockIdx.x * 256 + threadIdx.x;   // 655360 threads, 8 elems each
    long row = idx >> 3;            // bh*L + l
    int d0 = ((int)idx & 7) * 8;
    long bh = row >> 10, l = row & 1023;
    const float* p0 = Op + row * DH_ + d0;
    const float* p1 = Op + ((long)BH_ * L_ + row) * DH_ + d0;
    float rcp = 1.f / (Rs[row] + Rs[(long)BH_ * L_ + row]);
    float4 a0 = *(const float4*)p0, a1 = *(const float4*)(p0 + 4);
    float4 b0 = *(const float4*)p1, b1 = *(const float4*)(p1 + 4);
    float4 c0 = make_float4((a0.x + b0.x) * rcp, (a0.y + b0.y) * rcp,
                            (a0.z + b0.z) * rcp, (a0.w + b0.w) * rcp);
    float4 c1 = make_float4((a1.x + b1.x) * rcp, (a1.y + b1.y) * rcp,
                            (a1.z + b1.z) * rcp, (a1.w + b1.w) * rcp);
    long b = bh / H_, h = bh % H_;
    *(short8*)&Ctx[((b * L_ + l) * D_) + h * DH_ + d0] = pack8(c0, c1);
}

extern "C" void kernel_launch(void* const* d_in, const int* in_sizes, int n_in,
                              void* d_out, int out_size, void* d_ws, size_t ws_size,
                              hipStream_t stream) {
    const float* X   = (const float*)d_in[0];
    const float* Wq  = (const float*)d_in[1];
    const float* Wk  = (const float*)d_in[2];
    const float* Wv  = (const float*)d_in[3];
    const float* Wo  = (const float*)d_in[4];
    const float* bo  = (const float*)d_in[5];
    const float* Kbg = (const float*)d_in[6];
    const float* Vbg = (const float*)d_in[7];

    char* ws = (char*)d_ws;
    size_t off = 0;
    auto alloc = [&](size_t bytes) {
        void* p = ws + off;
        off = (off + bytes + 255) & ~(size_t)255;
        return p;
    };
    ushort* Wt    = (ushort*)alloc((size_t)4 * D_ * D_ * 2);     // Wq^T|Wk^T|Wv^T|Wo^T
    ushort* Qp    = (ushort*)alloc((size_t)BH_ * L_ * DH_ * 2);
    ushort* Kp    = (ushort*)alloc((size_t)BH_ * L_ * DH_ * 2);  // Kc fg tiles
    ushort* Kcv   = (ushort*)alloc((size_t)BH_ * L_ * DH_ * 2);  // Kc bg tiles
    ushort* Vt    = (ushort*)alloc((size_t)BH_ * DH_ * L2_ * 2); // Vc tiles (fg+bg)
    ushort* Xb    = (ushort*)alloc((size_t)B_ * L_ * D_ * 2);    // bf16(X); Ctx aliases
    float*  Opar  = (float*)alloc((size_t)2 * BH_ * L_ * DH_ * 4); // split-KV partial O
    float*  Rspar = (float*)alloc((size_t)2 * BH_ * L_ * 4);       // split-KV partial rs
    ushort* Ctx   = Xb;  // Xb dead after QKV GEMM; combine writes Ctx afterwards
    ushort* Wqkv_t = Wt;
    ushort* Wo_t   = Wt + (size_t)3 * D_ * D_;

    prep<<<6720, 256, 0, stream>>>(Wq, Wk, Wv, Wo, Wt, Vbg, Vt, X, Xb, Kbg, Kcv);
    // QKV projection: N = 3840 (Q|K|V), M = 4096 (R7 config: 128x128, 960 blocks)
    gemm_tpl<128, 128, 2, 2><<<dim3(30, 32), 256, 0, stream>>>(
        Xb, Wqkv_t, Qp, Kp, Vt, nullptr, nullptr, 0);
    // attention: split-KV, 1280 blocks x 256 threads (4 waves x 32 q)
    flash_attn<<<dim3(1280), 256, 0, stream>>>(Qp, Kp, Kcv, Vt, Opar, Rspar);
    // combine partials -> Ctx (bf16)
    combine<<<dim3(2560), 256, 0, stream>>>(Opar, Rspar, Ctx);
    // output projection (R7 config: 64x128, 640 blocks)
    gemm_tpl<64, 128, 1, 4><<<dim3(10, 64), 256, 0, stream>>>(
        Ctx, Wo_t, nullptr, nullptr, nullptr, (float*)d_out, bo, 1);
}

// Round 5
// 309.992 us; speedup vs baseline: 1.0079x; 1.0079x over previous
//
#include <hip/hip_runtime.h>
#include <hip/hip_bf16.h>

#define B_   4
#define L_   1024
#define D_   1280
#define H_   20
#define DH_  64
#define BH_  (B_*H_)     // 80
#define L2_  (2*L_)      // 2048
#define ALPHA_ 0.48f
// Q prescale: 0.125 (score scale) * log2(e) -> scores in log2 domain, exp = v_exp_f32
#define QSCALE_ 0.180336880f

typedef __attribute__((ext_vector_type(8))) short short8;
typedef __attribute__((ext_vector_type(4))) float float4v;

__device__ __forceinline__ float exp2_fast(float x) {
    float r;
    asm volatile("v_exp_f32 %0, %1" : "=v"(r) : "v"(x));
    return r;
}

__device__ __forceinline__ ushort f2bf(float f) {
    union { float f; unsigned int i; } v; v.f = f;
    unsigned int i = v.i;
    unsigned int r = i + 0x7FFF + ((i >> 16) & 1);  // RNE
    return (ushort)(r >> 16);
}
__device__ __forceinline__ short8 pack8(float4 f0, float4 f1) {
    short8 o;
    o[0] = (short)f2bf(f0.x); o[1] = (short)f2bf(f0.y);
    o[2] = (short)f2bf(f0.z); o[3] = (short)f2bf(f0.w);
    o[4] = (short)f2bf(f1.x); o[5] = (short)f2bf(f1.y);
    o[6] = (short)f2bf(f1.z); o[7] = (short)f2bf(f1.w);
    return o;
}
// pack 4 f32 -> 4 bf16 (RNE) and store as one 8-byte write
__device__ __forceinline__ void pack4_store(ushort* dst, float a, float b, float c, float d) {
    union { __hip_bfloat162 h; unsigned int u; } x, y;
    x.h = __float22bfloat162_rn(make_float2(a, b));
    y.h = __float22bfloat162_rn(make_float2(c, d));
    uint2 v; v.x = x.u; v.y = y.u;
    *(uint2*)dst = v;
}

// async global->LDS, 16 B per lane; dest = wave-uniform base + lane*16
__device__ __forceinline__ void async16(const void* g, void* l) {
    __builtin_amdgcn_global_load_lds(
        (__attribute__((address_space(1))) void*)g,
        (__attribute__((address_space(3))) void*)l, 16, 0, 0);
}

// ---------------- fused prep (inputs f32) -------------------------------------------
// K/V stored in flash-staging tile order so flash's global_load_lds is coalesced:
//   Kc tile  [bh][kt]      : elem (c*64 + kv)*8 + e  = bf16(K[kt*64+kv][c*8+e])
//   Vc tile  [bh][kt 0..31]: elem (cc*64 + d)*8 + e  = bf16((a)V[kt*64+rho(cc,e)][d])
// rho(cc,e) = (cc>>2)*32 + (e>>2)*16 + (cc&3)*4 + (e&3): V rows permuted relative to
// K rows so that flash's P fragment is lane-local (in-register P, no LDS round-trip).
// Softmax is permutation-invariant over kv, so this is exact.
// bi <  1600 : Wt[z][c][r] = bf16(w_z[r][c])          (weight transposes)
// bi <  2880 : Vc bg tiles (kt 16..31) from Vbg, alpha-scaled
// bi <  5440 : Xb  = bf16(X)
// bi <  6720 : Kc bg tiles from Kbg (unscaled; alpha applied on log2-scores in flash)
__global__ __launch_bounds__(256) void prep(
    const float* __restrict__ w0, const float* __restrict__ w1,
    const float* __restrict__ w2, const float* __restrict__ w3,
    ushort* __restrict__ Wt,
    const float* __restrict__ Vbg, ushort* __restrict__ Vt,
    const float* __restrict__ X, ushort* __restrict__ Xb,
    const float* __restrict__ Kbg, ushort* __restrict__ Kcv) {
    int bi = blockIdx.x, tid = threadIdx.x;
    __shared__ __align__(16) ushort t[64 * 72];
    if (bi < 2880) {
        bool doScale = (bi >= 1600);
        const float* src; int srcld; long sbase;
        ushort* dst = nullptr; int dstld = 0; long dbase = 0;  // W path
        ushort* vout = nullptr;                                // V path
        if (bi < 1600) {
            int z = bi / 400, t4 = bi % 400;
            int by = t4 / 20, bx = t4 % 20;
            const float* srcs[4] = {w0, w1, w2, w3};
            src = srcs[z]; srcld = D_; dstld = D_;
            sbase = (long)(by * 64) * D_ + bx * 64;
            dst = Wt + (long)z * D_ * D_;
            dbase = (long)(bx * 64) * D_ + by * 64;
        } else {
            int j = bi - 1600;          // 0..1279
            int bh = j >> 4, kt = j & 15;
            src = Vbg; srcld = DH_;
            sbase = ((long)bh * L_ + kt * 64) * DH_;
            vout = Vt + (((long)bh * 32 + 16 + kt) << 12);
        }
        int ldr = tid >> 3, ldc = (tid & 7) * 8;
#pragma unroll
        for (int i = 0; i < 2; i++) {
            int y = ldr + 32 * i;
            long idx = sbase + (long)y * srcld + ldc;
            float4 f0 = *(const float4*)&src[idx];
            float4 f1 = *(const float4*)&src[idx + 4];
            if (doScale) {
                f0.x *= ALPHA_; f0.y *= ALPHA_; f0.z *= ALPHA_; f0.w *= ALPHA_;
                f1.x *= ALPHA_; f1.y *= ALPHA_; f1.z *= ALPHA_; f1.w *= ALPHA_;
            }
            *(short8*)&t[y * 72 + ldc] = pack8(f0, f1);
        }
        __syncthreads();
        if (bi < 1600) {
            int r8 = (tid & 7) * 8, c0 = tid >> 3;   // coalesced: wave covers 8 c-rows
#pragma unroll
            for (int i = 0; i < 2; i++) {
                int c = c0 + i * 32;
                short8 o;
#pragma unroll
                for (int j2 = 0; j2 < 8; j2++) o[j2] = (short)t[(r8 + j2) * 72 + c];
                *(short8*)&dst[dbase + (long)c * dstld + r8] = o;
            }
        } else {
            // Vc tile (rho-permuted): out chunk jj = cc*64 + d, elem e <- t[rho][d]
#pragma unroll
            for (int i = 0; i < 2; i++) {
                int jj = i * 256 + tid;
                int cc = jj >> 6, d2 = jj & 63;
                int rb = (cc >> 2) * 32 + (cc & 3) * 4;
                short8 o;
#pragma unroll
                for (int e = 0; e < 8; e++)
                    o[e] = (short)t[(rb + (e >> 2) * 16 + (e & 3)) * 72 + d2];
                *(short8*)&vout[(long)jj * 8] = o;
            }
        }
    } else if (bi < 5440) {
        long i = ((long)(bi - 2880) * 256 + tid) * 8;
        *(short8*)&Xb[i] = pack8(*(const float4*)&X[i], *(const float4*)&X[i + 4]);
    } else {
        // Kc bg tile permute: 16B-chunk reorder via LDS (coalesced both sides)
        int j2 = bi - 5440;             // 0..1279
        int bh = j2 >> 4, kt = j2 & 15;
        const float* src = Kbg + ((long)bh * L_ + kt * 64) * DH_;
#pragma unroll
        for (int i = 0; i < 2; i++) {
            int r = i * 256 + tid;      // chunk (kv, cd): coalesced 32B f32 reads
            int kv = r >> 3, cd = r & 7;
            long idx = (long)kv * 64 + cd * 8;
            *(short8*)&t[kv * 72 + cd * 8] =
                pack8(*(const float4*)&src[idx], *(const float4*)&src[idx + 4]);
        }
        __syncthreads();
        ushort* outp = Kcv + (((long)bh * 16 + kt) << 12);
#pragma unroll
        for (int i = 0; i < 2; i++) {
            int jj = i * 256 + tid;     // out chunk jj = c*64 + kv: coalesced writes
            int c = jj >> 6, kv = jj & 63;
            *(short8*)&outp[(long)jj * 8] = *(const short8*)&t[kv * 72 + c * 8];
        }
    }
}

// ---------------- GEMM (bf16): C[m][n] = sum_k A[m][k]*Bt[n][k], K=1280 --------------
// Double-buffered async LDS staging, one barrier per K-iter (R7 config).
// mode 0: scatter -> Qp (x QSCALE_), Kc tiles, Vc tiles (rho-permuted)
// mode 1: Out(f32) = acc + bo[n]
template<int BMt, int BNt, int WROWS, int WCOLS>
__global__ __launch_bounds__(256) void gemm_tpl(
    const ushort* __restrict__ A, const ushort* __restrict__ Bt,
    ushort* __restrict__ Qp, ushort* __restrict__ Kp, ushort* __restrict__ Vt,
    float* __restrict__ Out, const float* __restrict__ bo, int mode) {
    constexpr int MI = BMt / WROWS / 16;
    constexpr int NI = BNt / WCOLS / 16;
    constexpr int ASZ = BMt * 32, BSZ = BNt * 32;
    constexpr int RB = 1280 / BNt;  // blocks per 1280-wide output region
    __shared__ __align__(16) ushort Al[2 * ASZ];
    __shared__ __align__(16) ushort Bl[2 * BSZ];
    int tid = threadIdx.x;
    int bx = blockIdx.x, by = blockIdx.y;
    int w = tid >> 6, lane = tid & 63, l15 = lane & 15, quad = lane >> 4;
    int wm = (w / WCOLS) * (BMt / WROWS);
    int wn = (w % WCOLS) * (BNt / WCOLS);
    float4v acc[MI][NI] = {};
    const int K = 1280;
    constexpr int NK = 40;
    const ushort* Arow = A + (long)by * BMt * K + (tid >> 2) * K + (tid & 3) * 8;
    const ushort* Brow = Bt + (long)bx * BNt * K + (tid >> 2) * K + (tid & 3) * 8;

    auto stage = [&](int ki, int b) {
#pragma unroll
        for (int i = 0; i < BMt / 64; i++)
            async16(Arow + (long)i * 64 * K + ki * 32, &Al[b * ASZ + (i * 4 + w) * 512]);
#pragma unroll
        for (int i = 0; i < BNt / 64; i++)
            async16(Brow + (long)i * 64 * K + ki * 32, &Bl[b * BSZ + (i * 4 + w) * 512]);
    };

    stage(0, 0);
    __syncthreads();
    for (int ki = 0; ki < NK; ki++) {
        int cur = ki & 1;
        if (ki + 1 < NK) stage(ki + 1, 1 - cur);
        short8 av[MI], bv[NI];
#pragma unroll
        for (int mi = 0; mi < MI; mi++)
            av[mi] = *(const short8*)&Al[cur * ASZ + (wm + mi * 16 + l15) * 32 + quad * 8];
#pragma unroll
        for (int ni = 0; ni < NI; ni++)
            bv[ni] = *(const short8*)&Bl[cur * BSZ + (wn + ni * 16 + l15) * 32 + quad * 8];
#pragma unroll
        for (int mi = 0; mi < MI; mi++)
#pragma unroll
            for (int ni = 0; ni < NI; ni++)
                acc[mi][ni] = __builtin_amdgcn_mfma_f32_16x16x32_bf16(av[mi], bv[ni], acc[mi][ni], 0, 0, 0);
        __syncthreads();
    }

    if (mode == 0) {
        int which = bx / RB;
#pragma unroll
        for (int mi = 0; mi < MI; mi++) {
            int m0 = by * BMt + wm + mi * 16 + quad * 4;
            int b = m0 >> 10, l0 = m0 & 1023;
#pragma unroll
            for (int ni = 0; ni < NI; ni++) {
                int n = bx * BNt + wn + ni * 16 + l15;
                int np = n - which * 1280;
                int h = np >> 6, dh = np & 63;
                if (which == 0) {
#pragma unroll
                    for (int r = 0; r < 4; r++)
                        Qp[((long)(b * H_ + h) * L_ + l0 + r) * DH_ + dh] =
                            f2bf(acc[mi][ni][r] * QSCALE_);
                } else if (which == 1) {
                    // Kc tile: elem ((bh*16+kt)*8 + dh/8)*512 + (kv&63)*8 + dh&7
                    long kb = ((((long)(b * H_ + h) * 16 + (l0 >> 6)) * 8 + (dh >> 3)) * 64
                               + (l0 & 63)) * 8 + (dh & 7);
#pragma unroll
                    for (int r = 0; r < 4; r++)
                        Kp[kb + r * 8] = f2bf(acc[mi][ni][r]);
                } else {
                    // Vc tile, rho-permuted rows: j = kv&63 ->
                    // cc = ((j>>5)<<2)|((j>>2)&3), elem base = ((j>>4)&1)<<2
                    int j = l0 & 63;
                    int cc = ((j >> 5) << 2) | ((j >> 2) & 3);
                    int eb = ((j >> 4) & 1) << 2;
                    pack4_store(&Vt[((((long)(b * H_ + h) * 32 + (l0 >> 6)) * 8
                                      + cc) * 64 + dh) * 8 + eb],
                                acc[mi][ni][0], acc[mi][ni][1],
                                acc[mi][ni][2], acc[mi][ni][3]);
                }
            }
        }
    } else {
#pragma unroll
        for (int mi = 0; mi < MI; mi++) {
            int mloc = wm + mi * 16 + quad * 4;
#pragma unroll
            for (int ni = 0; ni < NI; ni++) {
                int nloc = wn + ni * 16 + l15;
#pragma unroll
                for (int r = 0; r < 4; r++) {
                    int m = by * BMt + mloc + r;
                    int n = bx * BNt + nloc;
                    Out[(long)m * D_ + n] = acc[mi][ni][r] + bo[n];
                }
            }
        }
    }
}

// ---------------- flash attention: 4 waves x 32 q rows, IN-REGISTER P ---------------
// R12: split-KV reverted (combine ate its gain). P no longer round-trips through LDS:
// V rows are rho-permuted (producers above) so the PV B-fragment element (quad,ks,e)
// is exactly exp(s4[2ks+(e>>2)][e&3]) -- already lane-local. Deletes the 18.4KB Pl
// buffer (LDS 50->32KB, 3->4 blocks/CU), 12 LDS ops/iter and the full-wave
// lgkmcnt(0) fence on the per-iteration critical path.
__global__ __launch_bounds__(256) void flash_attn(
    const ushort* __restrict__ Qp, const ushort* __restrict__ Kp,
    const ushort* __restrict__ Kbg, const ushort* __restrict__ Vt,
    ushort* __restrict__ Ctx) {
    __shared__ __align__(16) ushort Kl[2 * 4096], Vl[2 * 4096];
    int tid = threadIdx.x;
    int w = tid >> 6, lane = tid & 63, l15 = lane & 15, quad = lane >> 4;
    int bi = blockIdx.x;
    int bh = (bi & 7) * 10 + ((bi >> 3) % 10);
    int qt = bi / 80;

    // Q fragments: wave w owns q rows qt*128 + w*32 .. +32 (loop-invariant)
    short8 aq[2][2];
    const ushort* Qb = Qp + ((long)bh * L_ + qt * 128 + w * 32) * DH_;
#pragma unroll
    for (int mi = 0; mi < 2; mi++)
#pragma unroll
        for (int ks = 0; ks < 2; ks++)
            aq[mi][ks] = *(const short8*)&Qb[(mi * 16 + l15) * DH_ + ks * 32 + quad * 8];

    float rs[2] = {0.f, 0.f};
    float4v O[2][4] = {};

    auto stage = [&](int kt, int b) {  // coalesced: tile base + c*1KB + lane*16B
        const ushort* Ksrc = (kt < 16)
            ? Kp  + (((long)bh * 16 + kt) << 12)
            : Kbg + (((long)bh * 16 + (kt - 16)) << 12);
        const ushort* Vsrc = Vt + (((long)bh * 32 + kt) << 12);
#pragma unroll
        for (int i = 0; i < 2; i++) {
            int c = w * 2 + i;
            async16(&Ksrc[c * 512 + lane * 8], &Kl[b * 4096 + c * 512]);
            async16(&Vsrc[c * 512 + lane * 8], &Vl[b * 4096 + c * 512]);
        }
    };

    stage(0, 0);
    __syncthreads();
    for (int kt = 0; kt < 32; kt++) {
        int cur = kt & 1;
        if (kt + 1 < 32) stage(kt + 1, 1 - cur);
        bool bg = (kt >= 16);
        // S^T = MFMA(A=K, B=Q): lane q = w*32+mi*16+l15, kv = nt*16+quad*4+r
        float4v s4[4][2] = {};
#pragma unroll
        for (int ks = 0; ks < 2; ks++) {
            short8 bk[4];
#pragma unroll
            for (int nt = 0; nt < 4; nt++)
                bk[nt] = *(const short8*)&Kl[cur * 4096 + (ks * 4 + quad) * 512 + (nt * 16 + l15) * 8];
#pragma unroll
            for (int nt = 0; nt < 4; nt++)
#pragma unroll
                for (int mi = 0; mi < 2; mi++)
                    s4[nt][mi] = __builtin_amdgcn_mfma_f32_16x16x32_bf16(bk[nt], aq[mi][ks], s4[nt][mi], 0, 0, 0);
        }
        // p = 2^s (alpha on bg log2-scores); rs lane-local; P stays in-register:
        // rho-permuted V rows make ap[ks] = bf16(p[2ks][0..3] , p[2ks+1][0..3])
        short8 ap[2][2];
#pragma unroll
        for (int mi = 0; mi < 2; mi++) {
            float p[4][4];
#pragma unroll
            for (int nt = 0; nt < 4; nt++)
#pragma unroll
                for (int r = 0; r < 4; r++) {
                    float sv = s4[nt][mi][r];
                    if (bg) sv *= ALPHA_;
                    p[nt][r] = exp2_fast(sv);
                    rs[mi] += p[nt][r];
                }
#pragma unroll
            for (int ks = 0; ks < 2; ks++) {
                float4 f0 = make_float4(p[2 * ks][0], p[2 * ks][1],
                                        p[2 * ks][2], p[2 * ks][3]);
                float4 f1 = make_float4(p[2 * ks + 1][0], p[2 * ks + 1][1],
                                        p[2 * ks + 1][2], p[2 * ks + 1][3]);
                ap[mi][ks] = pack8(f0, f1);
            }
        }
        // O^T += MFMA(A=V^T, B=P): lane q = l15 (+mi*16), d = nt*16+quad*4+r
#pragma unroll
        for (int ks = 0; ks < 2; ks++) {
            short8 bv[4];
#pragma unroll
            for (int nt = 0; nt < 4; nt++)
                bv[nt] = *(const short8*)&Vl[cur * 4096 + (ks * 4 + quad) * 512 + (nt * 16 + l15) * 8];
#pragma unroll
            for (int nt = 0; nt < 4; nt++)
#pragma unroll
                for (int mi = 0; mi < 2; mi++)
                    O[mi][nt] = __builtin_amdgcn_mfma_f32_16x16x32_bf16(bv[nt], ap[mi][ks], O[mi][nt], 0, 0, 0);
        }
        __syncthreads();  // prefetch complete + all waves done with cur buffer
    }
    // rs partials live across the 4 quads of each q: reduce with 2 shuffles
    int b = bh / H_, h = bh % H_;
#pragma unroll
    for (int mi = 0; mi < 2; mi++) {
        float v = rs[mi];
        v += __shfl_xor(v, 16);
        v += __shfl_xor(v, 32);
        float rcp = 1.f / v;
        // Ctx[b*L+l][h*64+dh]: lane has l fixed, dh = nt*16+quad*4+r -> 8B packed
        long l = qt * 128 + w * 32 + mi * 16 + l15;
#pragma unroll
        for (int nt = 0; nt < 4; nt++)
            pack4_store(&Ctx[(long)(b * L_ + l) * D_ + h * DH_ + nt * 16 + quad * 4],
                        O[mi][nt][0] * rcp, O[mi][nt][1] * rcp,
                        O[mi][nt][2] * rcp, O[mi][nt][3] * rcp);
    }
}

extern "C" void kernel_launch(void* const* d_in, const int* in_sizes, int n_in,
                              void* d_out, int out_size, void* d_ws, size_t ws_size,
                              hipStream_t stream) {
    const float* X   = (const float*)d_in[0];
    const float* Wq  = (const float*)d_in[1];
    const float* Wk  = (const float*)d_in[2];
    const float* Wv  = (const float*)d_in[3];
    const float* Wo  = (const float*)d_in[4];
    const float* bo  = (const float*)d_in[5];
    const float* Kbg = (const float*)d_in[6];
    const float* Vbg = (const float*)d_in[7];

    char* ws = (char*)d_ws;
    size_t off = 0;
    auto alloc = [&](size_t bytes) {
        void* p = ws + off;
        off = (off + bytes + 255) & ~(size_t)255;
        return p;
    };
    ushort* Wt    = (ushort*)alloc((size_t)4 * D_ * D_ * 2);     // Wq^T|Wk^T|Wv^T|Wo^T
    ushort* Qp    = (ushort*)alloc((size_t)BH_ * L_ * DH_ * 2);
    ushort* Kp    = (ushort*)alloc((size_t)BH_ * L_ * DH_ * 2);  // Kc fg tiles
    ushort* Kcv   = (ushort*)alloc((size_t)BH_ * L_ * DH_ * 2);  // Kc bg tiles
    ushort* Vt    = (ushort*)alloc((size_t)BH_ * DH_ * L2_ * 2); // Vc tiles (fg+bg)
    ushort* Xb    = (ushort*)alloc((size_t)B_ * L_ * D_ * 2);    // bf16(X); Ctx aliases
    ushort* Ctx   = Xb;  // Xb dead after QKV GEMM; flash writes Ctx afterwards
    ushort* Wqkv_t = Wt;
    ushort* Wo_t   = Wt + (size_t)3 * D_ * D_;

    prep<<<6720, 256, 0, stream>>>(Wq, Wk, Wv, Wo, Wt, Vbg, Vt, X, Xb, Kbg, Kcv);
    // QKV projection: N = 3840 (Q|K|V), M = 4096 (R7 config: 128x128, 960 blocks)
    gemm_tpl<128, 128, 2, 2><<<dim3(30, 32), 256, 0, stream>>>(
        Xb, Wqkv_t, Qp, Kp, Vt, nullptr, nullptr, 0);
    // attention: 640 blocks x 256 threads (4 waves x 32 q), XCD-swizzled, dbuf
    flash_attn<<<dim3(640), 256, 0, stream>>>(Qp, Kp, Kcv, Vt, Ctx);
    // output projection (R7 config: 64x128, 640 blocks)
    gemm_tpl<64, 128, 1, 4><<<dim3(10, 64), 256, 0, stream>>>(
        Ctx, Wo_t, nullptr, nullptr, nullptr, (float*)d_out, bo, 1);
}

// Round 6
// 302.841 us; speedup vs baseline: 1.0317x; 1.0236x over previous
//
#include <hip/hip_runtime.h>
#include <hip/hip_bf16.h>

#define B_   4
#define L_   1024
#define D_   1280
#define H_   20
#define DH_  64
#define BH_  (B_*H_)     // 80
#define L2_  (2*L_)      // 2048
#define ALPHA_ 0.48f
// Q prescale: 0.125 (score scale) * log2(e) -> scores in log2 domain, exp = v_exp_f32
#define QSCALE_ 0.180336880f

typedef __attribute__((ext_vector_type(8))) short short8;
typedef __attribute__((ext_vector_type(4))) float float4v;

__device__ __forceinline__ float exp2_fast(float x) {
    float r;
    asm volatile("v_exp_f32 %0, %1" : "=v"(r) : "v"(x));
    return r;
}

__device__ __forceinline__ ushort f2bf(float f) {
    union { float f; unsigned int i; } v; v.f = f;
    unsigned int i = v.i;
    unsigned int r = i + 0x7FFF + ((i >> 16) & 1);  // RNE
    return (ushort)(r >> 16);
}
__device__ __forceinline__ short8 pack8(float4 f0, float4 f1) {
    short8 o;
    o[0] = (short)f2bf(f0.x); o[1] = (short)f2bf(f0.y);
    o[2] = (short)f2bf(f0.z); o[3] = (short)f2bf(f0.w);
    o[4] = (short)f2bf(f1.x); o[5] = (short)f2bf(f1.y);
    o[6] = (short)f2bf(f1.z); o[7] = (short)f2bf(f1.w);
    return o;
}
// pack 4 f32 -> 4 bf16 (RNE) and store as one 8-byte write
__device__ __forceinline__ void pack4_store(ushort* dst, float a, float b, float c, float d) {
    union { __hip_bfloat162 h; unsigned int u; } x, y;
    x.h = __float22bfloat162_rn(make_float2(a, b));
    y.h = __float22bfloat162_rn(make_float2(c, d));
    uint2 v; v.x = x.u; v.y = y.u;
    *(uint2*)dst = v;
}

// async global->LDS, 16 B per lane; dest = wave-uniform base + lane*16
__device__ __forceinline__ void async16(const void* g, void* l) {
    __builtin_amdgcn_global_load_lds(
        (__attribute__((address_space(1))) void*)g,
        (__attribute__((address_space(3))) void*)l, 16, 0, 0);
}

// ---------------- fused prep (inputs f32) -------------------------------------------
// K/V stored in flash-staging tile order so flash's global_load_lds is coalesced:
//   Kc tile  [bh][kt]      : elem (c*64 + kv)*8 + e  = bf16(K[kt*64+kv][c*8+e])
//   Vc tile  [bh][kt 0..31]: elem (cc*64 + d)*8 + e  = bf16((a)V[kt*64+rho(cc,e)][d])
// rho(cc,e) = (cc>>2)*32 + (e>>2)*16 + (cc&3)*4 + (e&3): V rows permuted relative to
// K rows so that flash's P fragment is lane-local (in-register P, no LDS round-trip).
// Softmax is permutation-invariant over kv, so this is exact.
// bi <  1600 : Wt[z][c][r] = bf16(w_z[r][c])          (weight transposes)
// bi <  2880 : Vc bg tiles (kt 16..31) from Vbg, alpha-scaled
// bi <  5440 : Xb  = bf16(X)
// bi <  6720 : Kc bg tiles from Kbg (unscaled; alpha applied on log2-scores in flash)
__global__ __launch_bounds__(256) void prep(
    const float* __restrict__ w0, const float* __restrict__ w1,
    const float* __restrict__ w2, const float* __restrict__ w3,
    ushort* __restrict__ Wt,
    const float* __restrict__ Vbg, ushort* __restrict__ Vt,
    const float* __restrict__ X, ushort* __restrict__ Xb,
    const float* __restrict__ Kbg, ushort* __restrict__ Kcv) {
    int bi = blockIdx.x, tid = threadIdx.x;
    __shared__ __align__(16) ushort t[64 * 72];
    if (bi < 2880) {
        bool doScale = (bi >= 1600);
        const float* src; int srcld; long sbase;
        ushort* dst = nullptr; int dstld = 0; long dbase = 0;  // W path
        ushort* vout = nullptr;                                // V path
        if (bi < 1600) {
            int z = bi / 400, t4 = bi % 400;
            int by = t4 / 20, bx = t4 % 20;
            const float* srcs[4] = {w0, w1, w2, w3};
            src = srcs[z]; srcld = D_; dstld = D_;
            sbase = (long)(by * 64) * D_ + bx * 64;
            dst = Wt + (long)z * D_ * D_;
            dbase = (long)(bx * 64) * D_ + by * 64;
        } else {
            int j = bi - 1600;          // 0..1279
            int bh = j >> 4, kt = j & 15;
            src = Vbg; srcld = DH_;
            sbase = ((long)bh * L_ + kt * 64) * DH_;
            vout = Vt + (((long)bh * 32 + 16 + kt) << 12);
        }
        int ldr = tid >> 3, ldc = (tid & 7) * 8;
#pragma unroll
        for (int i = 0; i < 2; i++) {
            int y = ldr + 32 * i;
            long idx = sbase + (long)y * srcld + ldc;
            float4 f0 = *(const float4*)&src[idx];
            float4 f1 = *(const float4*)&src[idx + 4];
            if (doScale) {
                f0.x *= ALPHA_; f0.y *= ALPHA_; f0.z *= ALPHA_; f0.w *= ALPHA_;
                f1.x *= ALPHA_; f1.y *= ALPHA_; f1.z *= ALPHA_; f1.w *= ALPHA_;
            }
            *(short8*)&t[y * 72 + ldc] = pack8(f0, f1);
        }
        __syncthreads();
        if (bi < 1600) {
            int r8 = (tid & 7) * 8, c0 = tid >> 3;   // coalesced: wave covers 8 c-rows
#pragma unroll
            for (int i = 0; i < 2; i++) {
                int c = c0 + i * 32;
                short8 o;
#pragma unroll
                for (int j2 = 0; j2 < 8; j2++) o[j2] = (short)t[(r8 + j2) * 72 + c];
                *(short8*)&dst[dbase + (long)c * dstld + r8] = o;
            }
        } else {
            // Vc tile (rho-permuted): out chunk jj = cc*64 + d, elem e <- t[rho][d]
#pragma unroll
            for (int i = 0; i < 2; i++) {
                int jj = i * 256 + tid;
                int cc = jj >> 6, d2 = jj & 63;
                int rb = (cc >> 2) * 32 + (cc & 3) * 4;
                short8 o;
#pragma unroll
                for (int e = 0; e < 8; e++)
                    o[e] = (short)t[(rb + (e >> 2) * 16 + (e & 3)) * 72 + d2];
                *(short8*)&vout[(long)jj * 8] = o;
            }
        }
    } else if (bi < 5440) {
        long i = ((long)(bi - 2880) * 256 + tid) * 8;
        *(short8*)&Xb[i] = pack8(*(const float4*)&X[i], *(const float4*)&X[i + 4]);
    } else {
        // Kc bg tile permute: 16B-chunk reorder via LDS (coalesced both sides)
        int j2 = bi - 5440;             // 0..1279
        int bh = j2 >> 4, kt = j2 & 15;
        const float* src = Kbg + ((long)bh * L_ + kt * 64) * DH_;
#pragma unroll
        for (int i = 0; i < 2; i++) {
            int r = i * 256 + tid;      // chunk (kv, cd): coalesced 32B f32 reads
            int kv = r >> 3, cd = r & 7;
            long idx = (long)kv * 64 + cd * 8;
            *(short8*)&t[kv * 72 + cd * 8] =
                pack8(*(const float4*)&src[idx], *(const float4*)&src[idx + 4]);
        }
        __syncthreads();
        ushort* outp = Kcv + (((long)bh * 16 + kt) << 12);
#pragma unroll
        for (int i = 0; i < 2; i++) {
            int jj = i * 256 + tid;     // out chunk jj = c*64 + kv: coalesced writes
            int c = jj >> 6, kv = jj & 63;
            *(short8*)&outp[(long)jj * 8] = *(const short8*)&t[kv * 72 + c * 8];
        }
    }
}

// ---------------- GEMM (bf16): C[m][n] = sum_k A[m][k]*Bt[n][k], K=1280 --------------
// Double-buffered async LDS staging, one barrier per K-iter (R7 config).
// mode 0: scatter -> Qp (x QSCALE_), Kc tiles, Vc tiles (rho-permuted)
// mode 1: Out(f32) = acc + bo[n]
template<int BMt, int BNt, int WROWS, int WCOLS>
__global__ __launch_bounds__(256) void gemm_tpl(
    const ushort* __restrict__ A, const ushort* __restrict__ Bt,
    ushort* __restrict__ Qp, ushort* __restrict__ Kp, ushort* __restrict__ Vt,
    float* __restrict__ Out, const float* __restrict__ bo, int mode) {
    constexpr int MI = BMt / WROWS / 16;
    constexpr int NI = BNt / WCOLS / 16;
    constexpr int ASZ = BMt * 32, BSZ = BNt * 32;
    constexpr int RB = 1280 / BNt;  // blocks per 1280-wide output region
    __shared__ __align__(16) ushort Al[2 * ASZ];
    __shared__ __align__(16) ushort Bl[2 * BSZ];
    int tid = threadIdx.x;
    int bx = blockIdx.x, by = blockIdx.y;
    int w = tid >> 6, lane = tid & 63, l15 = lane & 15, quad = lane >> 4;
    int wm = (w / WCOLS) * (BMt / WROWS);
    int wn = (w % WCOLS) * (BNt / WCOLS);
    float4v acc[MI][NI] = {};
    const int K = 1280;
    constexpr int NK = 40;
    const ushort* Arow = A + (long)by * BMt * K + (tid >> 2) * K + (tid & 3) * 8;
    const ushort* Brow = Bt + (long)bx * BNt * K + (tid >> 2) * K + (tid & 3) * 8;

    auto stage = [&](int ki, int b) {
#pragma unroll
        for (int i = 0; i < BMt / 64; i++)
            async16(Arow + (long)i * 64 * K + ki * 32, &Al[b * ASZ + (i * 4 + w) * 512]);
#pragma unroll
        for (int i = 0; i < BNt / 64; i++)
            async16(Brow + (long)i * 64 * K + ki * 32, &Bl[b * BSZ + (i * 4 + w) * 512]);
    };

    stage(0, 0);
    __syncthreads();
    for (int ki = 0; ki < NK; ki++) {
        int cur = ki & 1;
        if (ki + 1 < NK) stage(ki + 1, 1 - cur);
        short8 av[MI], bv[NI];
#pragma unroll
        for (int mi = 0; mi < MI; mi++)
            av[mi] = *(const short8*)&Al[cur * ASZ + (wm + mi * 16 + l15) * 32 + quad * 8];
#pragma unroll
        for (int ni = 0; ni < NI; ni++)
            bv[ni] = *(const short8*)&Bl[cur * BSZ + (wn + ni * 16 + l15) * 32 + quad * 8];
#pragma unroll
        for (int mi = 0; mi < MI; mi++)
#pragma unroll
            for (int ni = 0; ni < NI; ni++)
                acc[mi][ni] = __builtin_amdgcn_mfma_f32_16x16x32_bf16(av[mi], bv[ni], acc[mi][ni], 0, 0, 0);
        __syncthreads();
    }

    if (mode == 0) {
        int which = bx / RB;
#pragma unroll
        for (int mi = 0; mi < MI; mi++) {
            int m0 = by * BMt + wm + mi * 16 + quad * 4;
            int b = m0 >> 10, l0 = m0 & 1023;
#pragma unroll
            for (int ni = 0; ni < NI; ni++) {
                int n = bx * BNt + wn + ni * 16 + l15;
                int np = n - which * 1280;
                int h = np >> 6, dh = np & 63;
                if (which == 0) {
#pragma unroll
                    for (int r = 0; r < 4; r++)
                        Qp[((long)(b * H_ + h) * L_ + l0 + r) * DH_ + dh] =
                            f2bf(acc[mi][ni][r] * QSCALE_);
                } else if (which == 1) {
                    // Kc tile: elem ((bh*16+kt)*8 + dh/8)*512 + (kv&63)*8 + dh&7
                    long kb = ((((long)(b * H_ + h) * 16 + (l0 >> 6)) * 8 + (dh >> 3)) * 64
                               + (l0 & 63)) * 8 + (dh & 7);
#pragma unroll
                    for (int r = 0; r < 4; r++)
                        Kp[kb + r * 8] = f2bf(acc[mi][ni][r]);
                } else {
                    // Vc tile, rho-permuted rows: j = kv&63 ->
                    // cc = ((j>>5)<<2)|((j>>2)&3), elem base = ((j>>4)&1)<<2
                    int j = l0 & 63;
                    int cc = ((j >> 5) << 2) | ((j >> 2) & 3);
                    int eb = ((j >> 4) & 1) << 2;
                    pack4_store(&Vt[((((long)(b * H_ + h) * 32 + (l0 >> 6)) * 8
                                      + cc) * 64 + dh) * 8 + eb],
                                acc[mi][ni][0], acc[mi][ni][1],
                                acc[mi][ni][2], acc[mi][ni][3]);
                }
            }
        }
    } else {
#pragma unroll
        for (int mi = 0; mi < MI; mi++) {
            int mloc = wm + mi * 16 + quad * 4;
#pragma unroll
            for (int ni = 0; ni < NI; ni++) {
                int nloc = wn + ni * 16 + l15;
#pragma unroll
                for (int r = 0; r < 4; r++) {
                    int m = by * BMt + mloc + r;
                    int n = bx * BNt + nloc;
                    Out[(long)m * D_ + n] = acc[mi][ni][r] + bo[n];
                }
            }
        }
    }
}

// ---------------- flash attention: q-split, 1280 blocks x 4 waves x 16 q rows -------
// R13: R5's ledger shows the kernel is TLP/latency-bound (occupancy 19%, both pipes
// <50%, every intra-iteration cut neutral; R4's block-count increase was the one win
// but its combine pass ate it). Split along q instead: 1280 blocks = 80 bh x 16
// q-tiles of 64 rows -- fully independent, no partials, no combine. Exactly 5
// blocks/CU (perfect balance) x 4 waves = up to 20 waves/CU (was 10, imbalanced).
// Per-wave chain halves (16 S-values/lane/iter). ap packed via v_cvt_pk_bf16_f32
// (1 VALU/2 elems vs ~5/elem f2bf; identical RNE bits on positive finites).
__global__ __launch_bounds__(256) void flash_attn(
    const ushort* __restrict__ Qp, const ushort* __restrict__ Kp,
    const ushort* __restrict__ Kbg, const ushort* __restrict__ Vt,
    ushort* __restrict__ Ctx) {
    __shared__ __align__(16) ushort Kl[2 * 4096], Vl[2 * 4096];
    int tid = threadIdx.x;
    int w = tid >> 6, lane = tid & 63, l15 = lane & 15, quad = lane >> 4;
    int bi = blockIdx.x;
    int bh = (bi & 7) * 10 + ((bi >> 3) % 10);   // same-bh blocks share bi&7 (XCD)
    int qt = bi / 80;                            // 0..15: 64-row q tile

    // Q fragments: wave w owns q rows qt*64 + w*16 .. +16 (loop-invariant)
    short8 aq[2];
    const ushort* Qb = Qp + ((long)bh * L_ + qt * 64 + w * 16) * DH_;
#pragma unroll
    for (int ks = 0; ks < 2; ks++)
        aq[ks] = *(const short8*)&Qb[l15 * DH_ + ks * 32 + quad * 8];

    float rs = 0.f;
    float4v O[4] = {};

    auto stage = [&](int kt, int b) {  // coalesced: tile base + c*1KB + lane*16B
        const ushort* Ksrc = (kt < 16)
            ? Kp  + (((long)bh * 16 + kt) << 12)
            : Kbg + (((long)bh * 16 + (kt - 16)) << 12);
        const ushort* Vsrc = Vt + (((long)bh * 32 + kt) << 12);
#pragma unroll
        for (int i = 0; i < 2; i++) {
            int c = w * 2 + i;
            async16(&Ksrc[c * 512 + lane * 8], &Kl[b * 4096 + c * 512]);
            async16(&Vsrc[c * 512 + lane * 8], &Vl[b * 4096 + c * 512]);
        }
    };

    stage(0, 0);
    __syncthreads();
    for (int kt = 0; kt < 32; kt++) {
        int cur = kt & 1;
        if (kt + 1 < 32) stage(kt + 1, 1 - cur);
        bool bg = (kt >= 16);
        // S^T = MFMA(A=K, B=Q): lane q = qt*64+w*16+l15, kv = nt*16+quad*4+r
        float4v s4[4] = {};
#pragma unroll
        for (int ks = 0; ks < 2; ks++) {
            short8 bk[4];
#pragma unroll
            for (int nt = 0; nt < 4; nt++)
                bk[nt] = *(const short8*)&Kl[cur * 4096 + (ks * 4 + quad) * 512 + (nt * 16 + l15) * 8];
#pragma unroll
            for (int nt = 0; nt < 4; nt++)
                s4[nt] = __builtin_amdgcn_mfma_f32_16x16x32_bf16(bk[nt], aq[ks], s4[nt], 0, 0, 0);
        }
        // p = 2^s (alpha on bg log2-scores); rs lane-local; P stays in-register:
        // rho-permuted V rows make ap[ks] = bf16(p[2ks][0..3] , p[2ks+1][0..3])
        float p[4][4];
#pragma unroll
        for (int nt = 0; nt < 4; nt++)
#pragma unroll
            for (int r = 0; r < 4; r++) {
                float sv = s4[nt][r];
                if (bg) sv *= ALPHA_;
                p[nt][r] = exp2_fast(sv);
                rs += p[nt][r];
            }
        short8 ap[2];
#pragma unroll
        for (int ks = 0; ks < 2; ks++) {
            union { __hip_bfloat162 h[4]; short8 s; } u;
            u.h[0] = __float22bfloat162_rn(make_float2(p[2 * ks][0], p[2 * ks][1]));
            u.h[1] = __float22bfloat162_rn(make_float2(p[2 * ks][2], p[2 * ks][3]));
            u.h[2] = __float22bfloat162_rn(make_float2(p[2 * ks + 1][0], p[2 * ks + 1][1]));
            u.h[3] = __float22bfloat162_rn(make_float2(p[2 * ks + 1][2], p[2 * ks + 1][3]));
            ap[ks] = u.s;
        }
        // O^T += MFMA(A=V^T, B=P): lane q = l15, d = nt*16+quad*4+r
#pragma unroll
        for (int ks = 0; ks < 2; ks++) {
            short8 bv[4];
#pragma unroll
            for (int nt = 0; nt < 4; nt++)
                bv[nt] = *(const short8*)&Vl[cur * 4096 + (ks * 4 + quad) * 512 + (nt * 16 + l15) * 8];
#pragma unroll
            for (int nt = 0; nt < 4; nt++)
                O[nt] = __builtin_amdgcn_mfma_f32_16x16x32_bf16(bv[nt], ap[ks], O[nt], 0, 0, 0);
        }
        __syncthreads();  // prefetch complete + all waves done with cur buffer
    }
    // rs partials live across the 4 quads of each q: reduce with 2 shuffles
    float v = rs;
    v += __shfl_xor(v, 16);
    v += __shfl_xor(v, 32);
    float rcp = 1.f / v;
    int b = bh / H_, h = bh % H_;
    long l = qt * 64 + w * 16 + l15;
#pragma unroll
    for (int nt = 0; nt < 4; nt++)
        pack4_store(&Ctx[(long)(b * L_ + l) * D_ + h * DH_ + nt * 16 + quad * 4],
                    O[nt][0] * rcp, O[nt][1] * rcp,
                    O[nt][2] * rcp, O[nt][3] * rcp);
}

extern "C" void kernel_launch(void* const* d_in, const int* in_sizes, int n_in,
                              void* d_out, int out_size, void* d_ws, size_t ws_size,
                              hipStream_t stream) {
    const float* X   = (const float*)d_in[0];
    const float* Wq  = (const float*)d_in[1];
    const float* Wk  = (const float*)d_in[2];
    const float* Wv  = (const float*)d_in[3];
    const float* Wo  = (const float*)d_in[4];
    const float* bo  = (const float*)d_in[5];
    const float* Kbg = (const float*)d_in[6];
    const float* Vbg = (const float*)d_in[7];

    char* ws = (char*)d_ws;
    size_t off = 0;
    auto alloc = [&](size_t bytes) {
        void* p = ws + off;
        off = (off + bytes + 255) & ~(size_t)255;
        return p;
    };
    ushort* Wt    = (ushort*)alloc((size_t)4 * D_ * D_ * 2);     // Wq^T|Wk^T|Wv^T|Wo^T
    ushort* Qp    = (ushort*)alloc((size_t)BH_ * L_ * DH_ * 2);
    ushort* Kp    = (ushort*)alloc((size_t)BH_ * L_ * DH_ * 2);  // Kc fg tiles
    ushort* Kcv   = (ushort*)alloc((size_t)BH_ * L_ * DH_ * 2);  // Kc bg tiles
    ushort* Vt    = (ushort*)alloc((size_t)BH_ * DH_ * L2_ * 2); // Vc tiles (fg+bg)
    ushort* Xb    = (ushort*)alloc((size_t)B_ * L_ * D_ * 2);    // bf16(X); Ctx aliases
    ushort* Ctx   = Xb;  // Xb dead after QKV GEMM; flash writes Ctx afterwards
    ushort* Wqkv_t = Wt;
    ushort* Wo_t   = Wt + (size_t)3 * D_ * D_;

    prep<<<6720, 256, 0, stream>>>(Wq, Wk, Wv, Wo, Wt, Vbg, Vt, X, Xb, Kbg, Kcv);
    // QKV projection: N = 3840 (Q|K|V), M = 4096 (R7 config: 128x128, 960 blocks)
    gemm_tpl<128, 128, 2, 2><<<dim3(30, 32), 256, 0, stream>>>(
        Xb, Wqkv_t, Qp, Kp, Vt, nullptr, nullptr, 0);
    // attention: q-split, 1280 blocks x 256 threads (4 waves x 16 q rows each)
    flash_attn<<<dim3(1280), 256, 0, stream>>>(Qp, Kp, Kcv, Vt, Ctx);
    // output projection (R7 config: 64x128, 640 blocks)
    gemm_tpl<64, 128, 1, 4><<<dim3(10, 64), 256, 0, stream>>>(
        Ctx, Wo_t, nullptr, nullptr, nullptr, (float*)d_out, bo, 1);
}

// Round 7
// 295.458 us; speedup vs baseline: 1.0574x; 1.0250x over previous
//
#include <hip/hip_runtime.h>
#include <hip/hip_bf16.h>

#define B_   4
#define L_   1024
#define D_   1280
#define H_   20
#define DH_  64
#define BH_  (B_*H_)     // 80
#define L2_  (2*L_)      // 2048
#define ALPHA_ 0.48f
// Q prescale: 0.125 (score scale) * log2(e) -> scores in log2 domain, exp = v_exp_f32
#define QSCALE_ 0.180336880f

typedef __attribute__((ext_vector_type(8))) short short8;
typedef __attribute__((ext_vector_type(4))) float float4v;

__device__ __forceinline__ float exp2_fast(float x) {
    float r;
    asm volatile("v_exp_f32 %0, %1" : "=v"(r) : "v"(x));
    return r;
}

__device__ __forceinline__ ushort f2bf(float f) {
    union { float f; unsigned int i; } v; v.f = f;
    unsigned int i = v.i;
    unsigned int r = i + 0x7FFF + ((i >> 16) & 1);  // RNE
    return (ushort)(r >> 16);
}
__device__ __forceinline__ short8 pack8(float4 f0, float4 f1) {
    short8 o;
    o[0] = (short)f2bf(f0.x); o[1] = (short)f2bf(f0.y);
    o[2] = (short)f2bf(f0.z); o[3] = (short)f2bf(f0.w);
    o[4] = (short)f2bf(f1.x); o[5] = (short)f2bf(f1.y);
    o[6] = (short)f2bf(f1.z); o[7] = (short)f2bf(f1.w);
    return o;
}
// pack 4 f32 -> 4 bf16 (RNE) and store as one 8-byte write
__device__ __forceinline__ void pack4_store(ushort* dst, float a, float b, float c, float d) {
    union { __hip_bfloat162 h; unsigned int u; } x, y;
    x.h = __float22bfloat162_rn(make_float2(a, b));
    y.h = __float22bfloat162_rn(make_float2(c, d));
    uint2 v; v.x = x.u; v.y = y.u;
    *(uint2*)dst = v;
}

// async global->LDS, 16 B per lane; dest = wave-uniform base + lane*16
__device__ __forceinline__ void async16(const void* g, void* l) {
    __builtin_amdgcn_global_load_lds(
        (__attribute__((address_space(1))) void*)g,
        (__attribute__((address_space(3))) void*)l, 16, 0, 0);
}

// ---------------- fused prep (inputs f32) -------------------------------------------
// K/V stored in flash-staging tile order so flash's global_load_lds is coalesced:
//   Kc tile  [bh][kt]      : elem (c*64 + kv)*8 + e  = bf16(K[kt*64+kv][c*8+e])
//   Vc tile  [bh][kt 0..31]: elem (cc*64 + d)*8 + e  = bf16((a)V[kt*64+rho(cc,e)][d])
// rho(cc,e) = (cc>>2)*32 + (e>>2)*16 + (cc&3)*4 + (e&3): V rows permuted relative to
// K rows so that flash's P fragment is lane-local (in-register P, no LDS round-trip).
// Softmax is permutation-invariant over kv, so this is exact.
// bi <  1600 : Wt[z][c][r] = bf16(w_z[r][c])          (weight transposes)
// bi <  2880 : Vc bg tiles (kt 16..31) from Vbg, alpha-scaled
// bi <  5440 : Xb  = bf16(X)
// bi <  6720 : Kc bg tiles from Kbg (unscaled; alpha applied on log2-scores in flash)
__global__ __launch_bounds__(256) void prep(
    const float* __restrict__ w0, const float* __restrict__ w1,
    const float* __restrict__ w2, const float* __restrict__ w3,
    ushort* __restrict__ Wt,
    const float* __restrict__ Vbg, ushort* __restrict__ Vt,
    const float* __restrict__ X, ushort* __restrict__ Xb,
    const float* __restrict__ Kbg, ushort* __restrict__ Kcv) {
    int bi = blockIdx.x, tid = threadIdx.x;
    __shared__ __align__(16) ushort t[64 * 72];
    if (bi < 2880) {
        bool doScale = (bi >= 1600);
        const float* src; int srcld; long sbase;
        ushort* dst = nullptr; int dstld = 0; long dbase = 0;  // W path
        ushort* vout = nullptr;                                // V path
        if (bi < 1600) {
            int z = bi / 400, t4 = bi % 400;
            int by = t4 / 20, bx = t4 % 20;
            const float* srcs[4] = {w0, w1, w2, w3};
            src = srcs[z]; srcld = D_; dstld = D_;
            sbase = (long)(by * 64) * D_ + bx * 64;
            dst = Wt + (long)z * D_ * D_;
            dbase = (long)(bx * 64) * D_ + by * 64;
        } else {
            int j = bi - 1600;          // 0..1279
            int bh = j >> 4, kt = j & 15;
            src = Vbg; srcld = DH_;
            sbase = ((long)bh * L_ + kt * 64) * DH_;
            vout = Vt + (((long)bh * 32 + 16 + kt) << 12);
        }
        int ldr = tid >> 3, ldc = (tid & 7) * 8;
#pragma unroll
        for (int i = 0; i < 2; i++) {
            int y = ldr + 32 * i;
            long idx = sbase + (long)y * srcld + ldc;
            float4 f0 = *(const float4*)&src[idx];
            float4 f1 = *(const float4*)&src[idx + 4];
            if (doScale) {
                f0.x *= ALPHA_; f0.y *= ALPHA_; f0.z *= ALPHA_; f0.w *= ALPHA_;
                f1.x *= ALPHA_; f1.y *= ALPHA_; f1.z *= ALPHA_; f1.w *= ALPHA_;
            }
            *(short8*)&t[y * 72 + ldc] = pack8(f0, f1);
        }
        __syncthreads();
        if (bi < 1600) {
            int r8 = (tid & 7) * 8, c0 = tid >> 3;   // coalesced: wave covers 8 c-rows
#pragma unroll
            for (int i = 0; i < 2; i++) {
                int c = c0 + i * 32;
                short8 o;
#pragma unroll
                for (int j2 = 0; j2 < 8; j2++) o[j2] = (short)t[(r8 + j2) * 72 + c];
                *(short8*)&dst[dbase + (long)c * dstld + r8] = o;
            }
        } else {
            // Vc tile (rho-permuted): out chunk jj = cc*64 + d, elem e <- t[rho][d]
#pragma unroll
            for (int i = 0; i < 2; i++) {
                int jj = i * 256 + tid;
                int cc = jj >> 6, d2 = jj & 63;
                int rb = (cc >> 2) * 32 + (cc & 3) * 4;
                short8 o;
#pragma unroll
                for (int e = 0; e < 8; e++)
                    o[e] = (short)t[(rb + (e >> 2) * 16 + (e & 3)) * 72 + d2];
                *(short8*)&vout[(long)jj * 8] = o;
            }
        }
    } else if (bi < 5440) {
        long i = ((long)(bi - 2880) * 256 + tid) * 8;
        *(short8*)&Xb[i] = pack8(*(const float4*)&X[i], *(const float4*)&X[i + 4]);
    } else {
        // Kc bg tile permute: 16B-chunk reorder via LDS (coalesced both sides)
        int j2 = bi - 5440;             // 0..1279
        int bh = j2 >> 4, kt = j2 & 15;
        const float* src = Kbg + ((long)bh * L_ + kt * 64) * DH_;
#pragma unroll
        for (int i = 0; i < 2; i++) {
            int r = i * 256 + tid;      // chunk (kv, cd): coalesced 32B f32 reads
            int kv = r >> 3, cd = r & 7;
            long idx = (long)kv * 64 + cd * 8;
            *(short8*)&t[kv * 72 + cd * 8] =
                pack8(*(const float4*)&src[idx], *(const float4*)&src[idx + 4]);
        }
        __syncthreads();
        ushort* outp = Kcv + (((long)bh * 16 + kt) << 12);
#pragma unroll
        for (int i = 0; i < 2; i++) {
            int jj = i * 256 + tid;     // out chunk jj = c*64 + kv: coalesced writes
            int c = jj >> 6, kv = jj & 63;
            *(short8*)&outp[(long)jj * 8] = *(const short8*)&t[kv * 72 + c * 8];
        }
    }
}

// ---------------- GEMM (bf16): C[m][n] = sum_k A[m][k]*Bt[n][k], K=1280 --------------
// R14: counted-vmcnt schedule (T4). The old __syncthreads() per K-iter emitted
// s_waitcnt vmcnt(0) -- draining the JUST-ISSUED prefetch for ki+1 before any wave
// proceeds. Now: stage(ki+1); vmcnt(NLD) waits only ki's loads (ki+1's stay in
// flight across the barrier, hidden under the whole next iteration); raw s_barrier
// pair covers cross-wave visibility + buffer-overwrite hazards.
// mode 0: scatter -> Qp (x QSCALE_), Kc tiles, Vc tiles (rho-permuted)
// mode 1: Out(f32) = acc + bo[n]
template<int BMt, int BNt, int WROWS, int WCOLS>
__global__ __launch_bounds__(256) void gemm_tpl(
    const ushort* __restrict__ A, const ushort* __restrict__ Bt,
    ushort* __restrict__ Qp, ushort* __restrict__ Kp, ushort* __restrict__ Vt,
    float* __restrict__ Out, const float* __restrict__ bo, int mode) {
    constexpr int MI = BMt / WROWS / 16;
    constexpr int NI = BNt / WCOLS / 16;
    constexpr int ASZ = BMt * 32, BSZ = BNt * 32;
    constexpr int RB = 1280 / BNt;  // blocks per 1280-wide output region
    constexpr int NLD = BMt / 64 + BNt / 64;  // async loads per wave per stage
    __shared__ __align__(16) ushort Al[2 * ASZ];
    __shared__ __align__(16) ushort Bl[2 * BSZ];
    int tid = threadIdx.x;
    int bx = blockIdx.x, by = blockIdx.y;
    int w = tid >> 6, lane = tid & 63, l15 = lane & 15, quad = lane >> 4;
    int wm = (w / WCOLS) * (BMt / WROWS);
    int wn = (w % WCOLS) * (BNt / WCOLS);
    float4v acc[MI][NI] = {};
    const int K = 1280;
    constexpr int NK = 40;
    const ushort* Arow = A + (long)by * BMt * K + (tid >> 2) * K + (tid & 3) * 8;
    const ushort* Brow = Bt + (long)bx * BNt * K + (tid >> 2) * K + (tid & 3) * 8;

    auto stage = [&](int ki, int b) {
#pragma unroll
        for (int i = 0; i < BMt / 64; i++)
            async16(Arow + (long)i * 64 * K + ki * 32, &Al[b * ASZ + (i * 4 + w) * 512]);
#pragma unroll
        for (int i = 0; i < BNt / 64; i++)
            async16(Brow + (long)i * 64 * K + ki * 32, &Bl[b * BSZ + (i * 4 + w) * 512]);
    };

    stage(0, 0);
    for (int ki = 0; ki < NK; ki++) {
        int cur = ki & 1;
        if (ki + 1 < NK) {
            stage(ki + 1, 1 - cur);
            if constexpr (NLD == 4) asm volatile("s_waitcnt vmcnt(4)" ::: "memory");
            else if constexpr (NLD == 3) asm volatile("s_waitcnt vmcnt(3)" ::: "memory");
            else asm volatile("s_waitcnt vmcnt(0)" ::: "memory");
        } else {
            asm volatile("s_waitcnt vmcnt(0)" ::: "memory");
        }
        __builtin_amdgcn_sched_barrier(0);
        __builtin_amdgcn_s_barrier();     // all waves' cur loads retired
        __builtin_amdgcn_sched_barrier(0);
        short8 av[MI], bv[NI];
#pragma unroll
        for (int mi = 0; mi < MI; mi++)
            av[mi] = *(const short8*)&Al[cur * ASZ + (wm + mi * 16 + l15) * 32 + quad * 8];
#pragma unroll
        for (int ni = 0; ni < NI; ni++)
            bv[ni] = *(const short8*)&Bl[cur * BSZ + (wn + ni * 16 + l15) * 32 + quad * 8];
#pragma unroll
        for (int mi = 0; mi < MI; mi++)
#pragma unroll
            for (int ni = 0; ni < NI; ni++)
                acc[mi][ni] = __builtin_amdgcn_mfma_f32_16x16x32_bf16(av[mi], bv[ni], acc[mi][ni], 0, 0, 0);
        __builtin_amdgcn_sched_barrier(0);
        __builtin_amdgcn_s_barrier();     // all waves done reading cur buffer
    }

    if (mode == 0) {
        int which = bx / RB;
#pragma unroll
        for (int mi = 0; mi < MI; mi++) {
            int m0 = by * BMt + wm + mi * 16 + quad * 4;
            int b = m0 >> 10, l0 = m0 & 1023;
#pragma unroll
            for (int ni = 0; ni < NI; ni++) {
                int n = bx * BNt + wn + ni * 16 + l15;
                int np = n - which * 1280;
                int h = np >> 6, dh = np & 63;
                if (which == 0) {
#pragma unroll
                    for (int r = 0; r < 4; r++)
                        Qp[((long)(b * H_ + h) * L_ + l0 + r) * DH_ + dh] =
                            f2bf(acc[mi][ni][r] * QSCALE_);
                } else if (which == 1) {
                    // Kc tile: elem ((bh*16+kt)*8 + dh/8)*512 + (kv&63)*8 + dh&7
                    long kb = ((((long)(b * H_ + h) * 16 + (l0 >> 6)) * 8 + (dh >> 3)) * 64
                               + (l0 & 63)) * 8 + (dh & 7);
#pragma unroll
                    for (int r = 0; r < 4; r++)
                        Kp[kb + r * 8] = f2bf(acc[mi][ni][r]);
                } else {
                    // Vc tile, rho-permuted rows: j = kv&63 ->
                    // cc = ((j>>5)<<2)|((j>>2)&3), elem base = ((j>>4)&1)<<2
                    int j = l0 & 63;
                    int cc = ((j >> 5) << 2) | ((j >> 2) & 3);
                    int eb = ((j >> 4) & 1) << 2;
                    pack4_store(&Vt[((((long)(b * H_ + h) * 32 + (l0 >> 6)) * 8
                                      + cc) * 64 + dh) * 8 + eb],
                                acc[mi][ni][0], acc[mi][ni][1],
                                acc[mi][ni][2], acc[mi][ni][3]);
                }
            }
        }
    } else {
#pragma unroll
        for (int mi = 0; mi < MI; mi++) {
            int mloc = wm + mi * 16 + quad * 4;
#pragma unroll
            for (int ni = 0; ni < NI; ni++) {
                int nloc = wn + ni * 16 + l15;
#pragma unroll
                for (int r = 0; r < 4; r++) {
                    int m = by * BMt + mloc + r;
                    int n = bx * BNt + nloc;
                    Out[(long)m * D_ + n] = acc[mi][ni][r] + bo[n];
                }
            }
        }
    }
}

// ---------------- flash attention: q-split + counted-vmcnt pipeline -----------------
// R14: same q-split geometry as R13 (1280 blocks x 4 waves x 16 q rows, 5 blocks/CU).
// Schedule change (T4): the end-of-iter __syncthreads() drained vmcnt(0) -- forcing
// the kt+1 prefetch to COMPLETE each iteration (overlap window = one compute phase
// ~350cyc vs L2/L3 latency 500-900cyc: the stall that survived R2/R3/R5's cuts).
// Now: stage(kt+1); vmcnt(4) waits only kt's 4 loads; kt+1's fly across both raw
// barriers, hidden under the entire iteration. Hazards: barrier-1 = collective
// cur-loads-retired (vmcnt in-order, m135); barrier-2 = all waves done reading cur
// before next stage overwrites it; no ds_writes; sched_barrier(0) fences (rule #18).
__global__ __launch_bounds__(256) void flash_attn(
    const ushort* __restrict__ Qp, const ushort* __restrict__ Kp,
    const ushort* __restrict__ Kbg, const ushort* __restrict__ Vt,
    ushort* __restrict__ Ctx) {
    __shared__ __align__(16) ushort Kl[2 * 4096], Vl[2 * 4096];
    int tid = threadIdx.x;
    int w = tid >> 6, lane = tid & 63, l15 = lane & 15, quad = lane >> 4;
    int bi = blockIdx.x;
    int bh = (bi & 7) * 10 + ((bi >> 3) % 10);   // same-bh blocks share bi&7 (XCD)
    int qt = bi / 80;                            // 0..15: 64-row q tile

    // Q fragments: wave w owns q rows qt*64 + w*16 .. +16 (loop-invariant)
    short8 aq[2];
    const ushort* Qb = Qp + ((long)bh * L_ + qt * 64 + w * 16) * DH_;
#pragma unroll
    for (int ks = 0; ks < 2; ks++)
        aq[ks] = *(const short8*)&Qb[l15 * DH_ + ks * 32 + quad * 8];

    float rs = 0.f;
    float4v O[4] = {};

    auto stage = [&](int kt, int b) {  // coalesced: tile base + c*1KB + lane*16B
        const ushort* Ksrc = (kt < 16)
            ? Kp  + (((long)bh * 16 + kt) << 12)
            : Kbg + (((long)bh * 16 + (kt - 16)) << 12);
        const ushort* Vsrc = Vt + (((long)bh * 32 + kt) << 12);
#pragma unroll
        for (int i = 0; i < 2; i++) {
            int c = w * 2 + i;
            async16(&Ksrc[c * 512 + lane * 8], &Kl[b * 4096 + c * 512]);
            async16(&Vsrc[c * 512 + lane * 8], &Vl[b * 4096 + c * 512]);
        }
    };

    stage(0, 0);
    for (int kt = 0; kt < 32; kt++) {
        int cur = kt & 1;
        if (kt + 1 < 32) {
            stage(kt + 1, 1 - cur);
            asm volatile("s_waitcnt vmcnt(4)" ::: "memory");  // kt's 4 done, kt+1's fly
        } else {
            asm volatile("s_waitcnt vmcnt(0)" ::: "memory");
        }
        __builtin_amdgcn_sched_barrier(0);
        __builtin_amdgcn_s_barrier();     // collective: cur buffer fully staged
        __builtin_amdgcn_sched_barrier(0);
        bool bg = (kt >= 16);
        // S^T = MFMA(A=K, B=Q): lane q = qt*64+w*16+l15, kv = nt*16+quad*4+r
        float4v s4[4] = {};
#pragma unroll
        for (int ks = 0; ks < 2; ks++) {
            short8 bk[4];
#pragma unroll
            for (int nt = 0; nt < 4; nt++)
                bk[nt] = *(const short8*)&Kl[cur * 4096 + (ks * 4 + quad) * 512 + (nt * 16 + l15) * 8];
#pragma unroll
            for (int nt = 0; nt < 4; nt++)
                s4[nt] = __builtin_amdgcn_mfma_f32_16x16x32_bf16(bk[nt], aq[ks], s4[nt], 0, 0, 0);
        }
        // p = 2^s (alpha on bg log2-scores); rs lane-local; P stays in-register:
        // rho-permuted V rows make ap[ks] = bf16(p[2ks][0..3] , p[2ks+1][0..3])
        float p[4][4];
#pragma unroll
        for (int nt = 0; nt < 4; nt++)
#pragma unroll
            for (int r = 0; r < 4; r++) {
                float sv = s4[nt][r];
                if (bg) sv *= ALPHA_;
                p[nt][r] = exp2_fast(sv);
                rs += p[nt][r];
            }
        short8 ap[2];
#pragma unroll
        for (int ks = 0; ks < 2; ks++) {
            union { __hip_bfloat162 h[4]; short8 s; } u;
            u.h[0] = __float22bfloat162_rn(make_float2(p[2 * ks][0], p[2 * ks][1]));
            u.h[1] = __float22bfloat162_rn(make_float2(p[2 * ks][2], p[2 * ks][3]));
            u.h[2] = __float22bfloat162_rn(make_float2(p[2 * ks + 1][0], p[2 * ks + 1][1]));
            u.h[3] = __float22bfloat162_rn(make_float2(p[2 * ks + 1][2], p[2 * ks + 1][3]));
            ap[ks] = u.s;
        }
        // O^T += MFMA(A=V^T, B=P): lane q = l15, d = nt*16+quad*4+r
#pragma unroll
        for (int ks = 0; ks < 2; ks++) {
            short8 bv[4];
#pragma unroll
            for (int nt = 0; nt < 4; nt++)
                bv[nt] = *(const short8*)&Vl[cur * 4096 + (ks * 4 + quad) * 512 + (nt * 16 + l15) * 8];
#pragma unroll
            for (int nt = 0; nt < 4; nt++)
                O[nt] = __builtin_amdgcn_mfma_f32_16x16x32_bf16(bv[nt], ap[ks], O[nt], 0, 0, 0);
        }
        __builtin_amdgcn_sched_barrier(0);
        __builtin_amdgcn_s_barrier();     // all waves done reading cur buffer
    }
    // rs partials live across the 4 quads of each q: reduce with 2 shuffles
    float v = rs;
    v += __shfl_xor(v, 16);
    v += __shfl_xor(v, 32);
    float rcp = 1.f / v;
    int b = bh / H_, h = bh % H_;
    long l = qt * 64 + w * 16 + l15;
#pragma unroll
    for (int nt = 0; nt < 4; nt++)
        pack4_store(&Ctx[(long)(b * L_ + l) * D_ + h * DH_ + nt * 16 + quad * 4],
                    O[nt][0] * rcp, O[nt][1] * rcp,
                    O[nt][2] * rcp, O[nt][3] * rcp);
}

extern "C" void kernel_launch(void* const* d_in, const int* in_sizes, int n_in,
                              void* d_out, int out_size, void* d_ws, size_t ws_size,
                              hipStream_t stream) {
    const float* X   = (const float*)d_in[0];
    const float* Wq  = (const float*)d_in[1];
    const float* Wk  = (const float*)d_in[2];
    const float* Wv  = (const float*)d_in[3];
    const float* Wo  = (const float*)d_in[4];
    const float* bo  = (const float*)d_in[5];
    const float* Kbg = (const float*)d_in[6];
    const float* Vbg = (const float*)d_in[7];

    char* ws = (char*)d_ws;
    size_t off = 0;
    auto alloc = [&](size_t bytes) {
        void* p = ws + off;
        off = (off + bytes + 255) & ~(size_t)255;
        return p;
    };
    ushort* Wt    = (ushort*)alloc((size_t)4 * D_ * D_ * 2);     // Wq^T|Wk^T|Wv^T|Wo^T
    ushort* Qp    = (ushort*)alloc((size_t)BH_ * L_ * DH_ * 2);
    ushort* Kp    = (ushort*)alloc((size_t)BH_ * L_ * DH_ * 2);  // Kc fg tiles
    ushort* Kcv   = (ushort*)alloc((size_t)BH_ * L_ * DH_ * 2);  // Kc bg tiles
    ushort* Vt    = (ushort*)alloc((size_t)BH_ * DH_ * L2_ * 2); // Vc tiles (fg+bg)
    ushort* Xb    = (ushort*)alloc((size_t)B_ * L_ * D_ * 2);    // bf16(X); Ctx aliases
    ushort* Ctx   = Xb;  // Xb dead after QKV GEMM; flash writes Ctx afterwards
    ushort* Wqkv_t = Wt;
    ushort* Wo_t   = Wt + (size_t)3 * D_ * D_;

    prep<<<6720, 256, 0, stream>>>(Wq, Wk, Wv, Wo, Wt, Vbg, Vt, X, Xb, Kbg, Kcv);
    // QKV projection: N = 3840 (Q|K|V), M = 4096 (128x128, 960 blocks)
    gemm_tpl<128, 128, 2, 2><<<dim3(30, 32), 256, 0, stream>>>(
        Xb, Wqkv_t, Qp, Kp, Vt, nullptr, nullptr, 0);
    // attention: q-split, 1280 blocks x 256 threads (4 waves x 16 q rows each)
    flash_attn<<<dim3(1280), 256, 0, stream>>>(Qp, Kp, Kcv, Vt, Ctx);
    // output projection (64x128, 640 blocks)
    gemm_tpl<64, 128, 1, 4><<<dim3(10, 64), 256, 0, stream>>>(
        Ctx, Wo_t, nullptr, nullptr, nullptr, (float*)d_out, bo, 1);
}